// Round 1
// baseline (112.868 us; speedup 1.0000x reference)
//
#include <hip/hip_runtime.h>
#include <hip/hip_bf16.h>
#include <math.h>

// Problem constants
#define BATCH     128
#define MOBJ      64
#define HFULL     112
#define CROP0     28
#define CROPSZ    56            // 84 - 28
#define ROWS_PB   14            // rows per block (CROPSZ / 4)
#define ROWBLKS   4
#define TPB       256
#define HID       64
#define OUTK      36            // 3 * 12
#define INV2S2    0.125f        // 1 / (2 * 2^2)

// ---------------------------------------------------------------------------
// Kernel B: gaussian goal map (separable) + BCE over the 56x56 crop.
// grid = (BATCH, ROWBLKS), block = TPB
// out[0] += aux ; out[1] += aux
// ---------------------------------------------------------------------------
__global__ __launch_bounds__(TPB) void gauss_bce_kernel(
    const int* __restrict__ goal_pixel,   // [B,2] (col, row)
    const int* __restrict__ obj_list,     // [B,M,2] (col, row)
    const int* __restrict__ obj_num,      // [B]
    const int* __restrict__ road_mask,    // [B,112,112]
    const float* __restrict__ goal_logits,// [B,56,56]
    float* __restrict__ out)
{
    const int b    = blockIdx.x;
    const int row0 = blockIdx.y * ROWS_PB;     // local row start inside crop

    __shared__ float s_rowf[MOBJ][ROWS_PB];    // per-object row factors
    __shared__ float s_colf[MOBJ][CROPSZ];     // per-object col factors
    __shared__ float s_growf[ROWS_PB];         // goal row factors
    __shared__ float s_gcolf[CROPSZ];          // goal col factors
    __shared__ float s_red[TPB / 64];

    const int   n  = obj_num[b];
    const float xL = (float)goal_pixel[b * 2 + 1];   // row coord of goal
    const float yL = (float)goal_pixel[b * 2 + 0];   // col coord of goal

    // Goal separable factors
    for (int i = threadIdx.x; i < ROWS_PB + CROPSZ; i += TPB) {
        if (i < ROWS_PB) {
            float r = (float)(CROP0 + row0 + i);
            float d = r - xL;
            s_growf[i] = __expf(-d * d * INV2S2);
        } else {
            float c = (float)(CROP0 + (i - ROWS_PB));
            float d = c - yL;
            s_gcolf[i - ROWS_PB] = __expf(-d * d * INV2S2);
        }
    }

    // Object separable factors: n * (ROWS_PB + CROPSZ) entries
    for (int i = threadIdx.x; i < n * (ROWS_PB + CROPSZ); i += TPB) {
        int m = i / (ROWS_PB + CROPSZ);
        int r = i - m * (ROWS_PB + CROPSZ);
        int xo = obj_list[(b * MOBJ + m) * 2 + 1];   // row coord
        int yo = obj_list[(b * MOBJ + m) * 2 + 0];   // col coord
        if (r < ROWS_PB) {
            float rr = (float)(CROP0 + row0 + r);
            float d  = rr - (float)xo;
            s_rowf[m][r] = __expf(-d * d * INV2S2);
        } else {
            float cc = (float)(CROP0 + (r - ROWS_PB));
            float d  = cc - (float)yo;
            s_colf[m][r - ROWS_PB] = __expf(-d * d * INV2S2);
        }
    }
    __syncthreads();

    // Pixel loop: ROWS_PB * CROPSZ = 784 pixels, strided by TPB
    float aux = 0.0f;
    for (int p = threadIdx.x; p < ROWS_PB * CROPSZ; p += TPB) {
        int h = p / CROPSZ;
        int w = p - h * CROPSZ;

        float osum = 0.0f;
        for (int m = 0; m < n; ++m)
            osum = fmaf(s_rowf[m][h], s_colf[m][w], osum);

        float g  = s_growf[h] * s_gcolf[w];
        int   gh = CROP0 + row0 + h;
        int   gw = CROP0 + w;
        int   rm = road_mask[(b * HFULL + gh) * HFULL + gw];
        float gt = rm ? (0.5f + 0.5f * g - 0.5f * osum) : 0.0f;

        float x  = goal_logits[(b * CROPSZ + (row0 + h)) * CROPSZ + w];
        // stable softplus: log(1+exp(x)) = max(x,0) + log1p(exp(-|x|))
        float sp = fmaxf(x, 0.0f) + log1pf(__expf(-fabsf(x)));
        aux += sp - x * gt;
    }

    // Block reduction: wave shuffle then LDS across the 4 waves
    for (int off = 32; off > 0; off >>= 1)
        aux += __shfl_down(aux, off, 64);
    const int wid  = threadIdx.x >> 6;
    const int lane = threadIdx.x & 63;
    if (lane == 0) s_red[wid] = aux;
    __syncthreads();
    if (threadIdx.x == 0) {
        float t = s_red[0] + s_red[1] + s_red[2] + s_red[3];
        atomicAdd(&out[0], t);   // loss += aux contribution
        atomicAdd(&out[1], t);   // aux_loss
    }
}

// ---------------------------------------------------------------------------
// Kernel A: motion loss. One thread per batch element (128 threads, 1 block).
// out[0] += motion ; out[2] += motion
// ---------------------------------------------------------------------------
__global__ __launch_bounds__(BATCH) void motion_kernel(
    const int* __restrict__ gp,       // [B,2]
    const float* __restrict__ tpos,   // [B,12,2]
    const float* __restrict__ tyaw,   // [B,12,1]
    const float* __restrict__ w1,     // [2,64]
    const float* __restrict__ b1,     // [64]
    const float* __restrict__ w2,     // [64,36]
    const float* __restrict__ b2,     // [36]
    float* __restrict__ out)
{
    const int b  = threadIdx.x;
    const float x0 = (float)gp[b * 2 + 0];
    const float x1 = (float)gp[b * 2 + 1];

    float acc[OUTK];
#pragma unroll
    for (int k = 0; k < OUTK; ++k) acc[k] = b2[k];

    for (int j = 0; j < HID; ++j) {
        float hj = fmaxf(fmaf(x0, w1[j], fmaf(x1, w1[HID + j], b1[j])), 0.0f);
#pragma unroll
        for (int k = 0; k < OUTK; ++k)
            acc[k] = fmaf(hj, w2[j * OUTK + k], acc[k]);
    }

    float err = 0.0f;
#pragma unroll
    for (int k = 0; k < OUTK; ++k) {
        int t = k / 3, c = k - 3 * t;
        float tg = (c < 2) ? tpos[(b * 12 + t) * 2 + c] : tyaw[b * 12 + t];
        float d  = acc[k] - tg;
        err = fmaf(d, d, err);
    }
    err *= (1.0f / (BATCH * OUTK));   // mean over 128*36

    // wave reduce (2 waves in this 128-thread block)
    for (int off = 32; off > 0; off >>= 1)
        err += __shfl_down(err, off, 64);
    if ((threadIdx.x & 63) == 0) {
        atomicAdd(&out[0], err);
        atomicAdd(&out[2], err);
    }
}

extern "C" void kernel_launch(void* const* d_in, const int* in_sizes, int n_in,
                              void* d_out, int out_size, void* d_ws, size_t ws_size,
                              hipStream_t stream) {
    const int*   goal_pixel   = (const int*)d_in[0];
    const int*   obj_list     = (const int*)d_in[1];
    const int*   obj_num      = (const int*)d_in[2];
    const int*   road_mask    = (const int*)d_in[3];
    const float* goal_logits  = (const float*)d_in[4];
    const float* target_pos   = (const float*)d_in[5];
    const float* target_yaw   = (const float*)d_in[6];
    const float* w1           = (const float*)d_in[7];
    const float* b1           = (const float*)d_in[8];
    const float* w2           = (const float*)d_in[9];
    const float* b2           = (const float*)d_in[10];
    float* out = (float*)d_out;

    // d_out is poisoned before every launch — zero the 3 accumulators.
    hipMemsetAsync(out, 0, 3 * sizeof(float), stream);

    dim3 gridB(BATCH, ROWBLKS);
    gauss_bce_kernel<<<gridB, TPB, 0, stream>>>(
        goal_pixel, obj_list, obj_num, road_mask, goal_logits, out);

    motion_kernel<<<1, BATCH, 0, stream>>>(
        goal_pixel, target_pos, target_yaw, w1, b1, w2, b2, out);
}

// Round 2
// 93.215 us; speedup vs baseline: 1.2108x; 1.2108x over previous
//
#include <hip/hip_runtime.h>
#include <hip/hip_bf16.h>
#include <math.h>

// Problem constants
#define BATCH     128
#define MOBJ      64
#define HFULL     112
#define CROP0     28
#define CROPSZ    56            // 84 - 28
#define ROWBLKS   4             // row-groups per batch
#define ROWS_PB   14            // rows per block (56/4)
#define TPB       128
#define HID       64
#define OUTK      36            // 3 * 12
#define INV2S2    0.125f        // 1 / (2 * sigma^2), sigma = 2

// ws layout (floats): [0..511]  aux partial per gauss block (b*4 + ry)
//                     [512,513] motion partials (2 waves of the motion block)
#define WS_MOTION 512

// ---------------------------------------------------------------------------
// Kernel 1: fused gauss+BCE partials (blocks b<128) and motion MLP (b==128).
// grid = (129, 4), block = 128.
// ---------------------------------------------------------------------------
__global__ __launch_bounds__(TPB) void fused_partials(
    const int* __restrict__ goal_pixel,   // [B,2] (col, row)
    const int* __restrict__ obj_list,     // [B,M,2] (col, row)
    const int* __restrict__ obj_num,      // [B]
    const int* __restrict__ road_mask,    // [B,112,112]
    const float* __restrict__ goal_logits,// [B,56,56]
    const float* __restrict__ tpos,       // [B,12,2]
    const float* __restrict__ tyaw,       // [B,12,1]
    const float* __restrict__ w1,         // [2,64]
    const float* __restrict__ b1,         // [64]
    const float* __restrict__ w2,         // [64,36]
    const float* __restrict__ b2,         // [36]
    float* __restrict__ ws)
{
    const int b   = blockIdx.x;
    const int tid = threadIdx.x;

    // ---------------- motion MLP block ----------------
    if (b == BATCH) {
        if (blockIdx.y != 0) return;
        const int bb = tid;                       // one thread per batch elem
        const float x0 = (float)goal_pixel[bb * 2 + 0];
        const float x1 = (float)goal_pixel[bb * 2 + 1];

        float acc[OUTK];
#pragma unroll
        for (int k = 0; k < OUTK; ++k) acc[k] = b2[k];
        for (int j = 0; j < HID; ++j) {
            float hj = fmaxf(fmaf(x0, w1[j], fmaf(x1, w1[HID + j], b1[j])), 0.0f);
#pragma unroll
            for (int k = 0; k < OUTK; ++k)
                acc[k] = fmaf(hj, w2[j * OUTK + k], acc[k]);
        }
        float err = 0.0f;
#pragma unroll
        for (int k = 0; k < OUTK; ++k) {
            int t = k / 3, c = k - 3 * t;
            float tg = (c < 2) ? tpos[(bb * 12 + t) * 2 + c] : tyaw[bb * 12 + t];
            float d  = acc[k] - tg;
            err = fmaf(d, d, err);
        }
        err *= (1.0f / (BATCH * OUTK));
        for (int off = 32; off > 0; off >>= 1)
            err += __shfl_down(err, off, 64);
        if ((tid & 63) == 0) ws[WS_MOTION + (tid >> 6)] = err;
        return;
    }

    // ---------------- gauss + BCE block ----------------
    const int row0 = blockIdx.y * ROWS_PB;        // crop-local first row
    const int rq   = tid / CROPSZ;                // 0,1 active; 2 = idle lanes
    const int w    = tid - rq * CROPSZ;

    // s_rowf[m][j]: j in [0,8) -> rows row0+0..6 (j==7 pad=0)
    //              j in [8,16) -> rows row0+7..13 (j==15 pad=0)
    __shared__ float s_rowf[MOBJ][16];
    __shared__ float s_ycol[MOBJ];
    __shared__ float s_red[2];

    const int n = obj_num[b];

    // Stage per-object factors
    for (int i = tid; i < n * 16; i += TPB) {
        int m  = i >> 4;
        int j  = i & 15;
        int g  = j >> 3;
        int jj = j & 7;
        float v = 0.0f;
        if (jj < 7) {
            float xo = (float)obj_list[(b * MOBJ + m) * 2 + 1];  // row coord
            float r  = (float)(CROP0 + row0 + g * 7 + jj);
            float d  = r - xo;
            v = __expf(-d * d * INV2S2);
        }
        s_rowf[m][j] = v;
    }
    for (int m = tid; m < n; m += TPB)
        s_ycol[m] = (float)obj_list[(b * MOBJ + m) * 2 + 0];     // col coord
    __syncthreads();

    float aux = 0.0f;
    if (rq < 2) {
        const float wf = (float)(CROP0 + w);
        const float xL = (float)goal_pixel[b * 2 + 1];
        const float yL = (float)goal_pixel[b * 2 + 0];
        const float dC = wf - yL;
        const float gc = __expf(-dC * dC * INV2S2);

        float acc[8];
#pragma unroll
        for (int i = 0; i < 8; ++i) acc[i] = 0.0f;

        const float4* rowp = (const float4*)&s_rowf[0][rq * 8];
        for (int m = 0; m < n; ++m) {
            float yo = s_ycol[m];
            float d  = wf - yo;
            float cf = __expf(-d * d * INV2S2);
            float4 r0 = rowp[m * 4];       // s_rowf[m][rq*8 .. +3]
            float4 r1 = rowp[m * 4 + 1];   // s_rowf[m][rq*8+4 .. +7]
            acc[0] = fmaf(r0.x, cf, acc[0]);
            acc[1] = fmaf(r0.y, cf, acc[1]);
            acc[2] = fmaf(r0.z, cf, acc[2]);
            acc[3] = fmaf(r0.w, cf, acc[3]);
            acc[4] = fmaf(r1.x, cf, acc[4]);
            acc[5] = fmaf(r1.y, cf, acc[5]);
            acc[6] = fmaf(r1.z, cf, acc[6]);
            acc[7] = fmaf(r1.w, cf, acc[7]);
        }

#pragma unroll
        for (int i = 0; i < 7; ++i) {
            int   h  = row0 + rq * 7 + i;      // crop-local row
            int   gh = CROP0 + h;              // full-image row
            float dr = (float)gh - xL;
            float g  = __expf(-dr * dr * INV2S2) * gc;
            int   rm = road_mask[(b * HFULL + gh) * HFULL + (CROP0 + w)];
            float gt = rm ? (0.5f + 0.5f * g - 0.5f * acc[i]) : 0.0f;
            float x  = goal_logits[(b * CROPSZ + h) * CROPSZ + w];
            float sp = fmaxf(x, 0.0f) + log1pf(__expf(-fabsf(x)));
            aux += sp - x * gt;
        }
    }

    // Block reduce (2 waves)
    for (int off = 32; off > 0; off >>= 1)
        aux += __shfl_down(aux, off, 64);
    const int wid  = tid >> 6;
    if ((tid & 63) == 0) s_red[wid] = aux;
    __syncthreads();
    if (tid == 0)
        ws[b * ROWBLKS + blockIdx.y] = s_red[0] + s_red[1];
}

// ---------------------------------------------------------------------------
// Kernel 2: reduce 512 aux partials + 2 motion partials -> out[0..2].
// 1 block, 256 threads.
// ---------------------------------------------------------------------------
__global__ __launch_bounds__(256) void reduce_out(
    const float* __restrict__ ws, float* __restrict__ out)
{
    const int t = threadIdx.x;
    float a = ws[t] + ws[t + 256];
    for (int off = 32; off > 0; off >>= 1)
        a += __shfl_down(a, off, 64);
    __shared__ float s[4];
    if ((t & 63) == 0) s[t >> 6] = a;
    __syncthreads();
    if (t == 0) {
        float aux    = s[0] + s[1] + s[2] + s[3];
        float motion = ws[WS_MOTION] + ws[WS_MOTION + 1];
        out[0] = aux + motion;
        out[1] = aux;
        out[2] = motion;
    }
}

extern "C" void kernel_launch(void* const* d_in, const int* in_sizes, int n_in,
                              void* d_out, int out_size, void* d_ws, size_t ws_size,
                              hipStream_t stream) {
    const int*   goal_pixel  = (const int*)d_in[0];
    const int*   obj_list    = (const int*)d_in[1];
    const int*   obj_num     = (const int*)d_in[2];
    const int*   road_mask   = (const int*)d_in[3];
    const float* goal_logits = (const float*)d_in[4];
    const float* target_pos  = (const float*)d_in[5];
    const float* target_yaw  = (const float*)d_in[6];
    const float* w1          = (const float*)d_in[7];
    const float* b1          = (const float*)d_in[8];
    const float* w2          = (const float*)d_in[9];
    const float* b2          = (const float*)d_in[10];
    float* out = (float*)d_out;
    float* ws  = (float*)d_ws;

    dim3 grid1(BATCH + 1, ROWBLKS);
    fused_partials<<<grid1, TPB, 0, stream>>>(
        goal_pixel, obj_list, obj_num, road_mask, goal_logits,
        target_pos, target_yaw, w1, b1, w2, b2, ws);

    reduce_out<<<1, 256, 0, stream>>>(ws, out);
}